// Round 7
// baseline (287.862 us; speedup 1.0000x reference)
//
#include <hip/hip_runtime.h>
#include <hip/hip_fp16.h>

#define IRR    56
#define EF     48
#define WN     832
#define NEDGE  160000
#define NNODE  8000
#define TE     16          // edges per wave (= per block)
#define NT     64
#define NBLK   (NEDGE / TE)

#define SG_STRIDE 60       // floats (gather tile)
#define SH_STRIDE 72       // ushorts
#define SF_STRIDE 120      // ushorts (fp16 F, exactly 120 entries); sO overlays at stride 60 f32 (16B-aligned rows)

#define INV_SQRT3 0.5773502691896258f
#define INV_SQRT2 0.7071067811865476f
#define A_SCAL    0.22360679774997896f   // 1/sqrt(20)
#define A_VEC     0.20412414523193154f   // 1/sqrt(24)

typedef __bf16 bf16x8 __attribute__((ext_vector_type(8)));
typedef float  f32x4  __attribute__((ext_vector_type(4)));
typedef unsigned short u16x8 __attribute__((ext_vector_type(8)));
typedef unsigned short u16x4 __attribute__((ext_vector_type(4)));

__device__ __forceinline__ unsigned short f2bf(float f) {
    unsigned int u = __builtin_bit_cast(unsigned int, f);
    u += 0x7FFFu + ((u >> 16) & 1u);          // RNE
    return (unsigned short)(u >> 16);
}
__device__ __forceinline__ unsigned short f2h(float f) {
    __half h = __float2half(f);
    return __builtin_bit_cast(unsigned short, h);
}
__device__ __forceinline__ float h2f(unsigned short u) {
    __half h = __builtin_bit_cast(__half, u);
    return __half2float(h);
}

// ---- setup: zero hist + build bf16 transposed weight tables [n][64] ----
__global__ void k_setup(const float* __restrict__ w1, const float* __restrict__ b1,
                        const float* __restrict__ w2, const float* __restrict__ b2,
                        unsigned short* __restrict__ W1T, unsigned short* __restrict__ W2T,
                        int* __restrict__ hist)
{
    int i = blockIdx.x * 256 + threadIdx.x;
    if (i < NNODE) hist[i] = 0;
    if (i < EF * WN) { int k = i / WN, n = i - k * WN; W2T[n * 64 + k] = f2bf(w2[i]); }
    if (i < WN * 16) { int n = i >> 4, kk = EF + (i & 15); W2T[n * 64 + kk] = (kk == EF) ? f2bf(b2[n]) : (unsigned short)0; }
    if (i < EF * EF) { int k = i / EF, n = i - k * EF; W1T[n * 64 + k] = f2bf(w1[i]); }
    if (i < EF * 16) { int n = i >> 4, kk = EF + (i & 15); W1T[n * 64 + kk] = (kk == EF) ? f2bf(b1[n]) : (unsigned short)0; }
}

__global__ void k_hist(const int* __restrict__ edge_index, int* __restrict__ hist)
{
    int e = blockIdx.x * 256 + threadIdx.x;
    if (e < NEDGE) atomicAdd(&hist[edge_index[e]], 1);
}

// single-block exclusive scan of hist[8000] -> offs, cursor (shfl-based)
__global__ __launch_bounds__(1024) void k_scan(const int* __restrict__ hist,
                                               int* __restrict__ offs, int* __restrict__ cursor)
{
    __shared__ int wpart[16];
    const int t = threadIdx.x;
    const int lane = t & 63;
    const int w = t >> 6;
    const int base = t * 8;
    int v[8]; int tot = 0;
    #pragma unroll
    for (int j = 0; j < 8; j++) {
        int x = (base + j < NNODE) ? hist[base + j] : 0;
        v[j] = tot; tot += x;
    }
    int s = tot;
    #pragma unroll
    for (int d = 1; d < 64; d <<= 1) {
        int up = __shfl_up(s, d, 64);
        if (lane >= d) s += up;
    }
    if (lane == 63) wpart[w] = s;
    int texcl = s - tot;
    __syncthreads();
    if (t < 16) {
        int x = wpart[t];
        #pragma unroll
        for (int d = 1; d < 16; d <<= 1) {
            int up = __shfl_up(x, d, 64);
            if (lane >= d) x += up;
        }
        wpart[t] = x;
    }
    __syncthreads();
    int woff = (w > 0) ? wpart[w - 1] : 0;
    int boff = woff + texcl;
    #pragma unroll
    for (int j = 0; j < 8; j++) {
        if (base + j < NNODE) { int o = boff + v[j]; offs[base + j] = o; cursor[base + j] = o; }
    }
}

__global__ void k_fill(const int* __restrict__ edge_index,
                       int* __restrict__ cursor, int* __restrict__ eid)
{
    int e = blockIdx.x * 256 + threadIdx.x;
    if (e < NEDGE) {
        int pos = atomicAdd(&cursor[edge_index[e]], 1);
        eid[pos] = e;
    }
}

__global__ __launch_bounds__(NT, 4) void tp_fused(
    const float* __restrict__ node_attr,
    const float* __restrict__ edge_attr,
    const float* __restrict__ edge_sh,
    const int*   __restrict__ edge_index,
    const unsigned short* __restrict__ W1T,
    const unsigned short* __restrict__ W2T,
    unsigned short* __restrict__ tpB)
{
    __shared__ __align__(16) float sG[TE * SG_STRIDE];           // 3840B gather (dead after F-phase)
    __shared__ __align__(16) unsigned short sH[TE * SH_STRIDE];  // 2304B H^T
    __shared__ __align__(16) unsigned short sF[TE * SF_STRIDE];  // 3840B fp16 F; sO overlays (stride 60 f32, 16B-aligned)
    __shared__ float sS1[TE][4];
    __shared__ int   sDst[TE];

    const int lane = threadIdx.x;
    const int m    = lane & 15;
    const int quad = lane >> 4;
    const int e0   = blockIdx.x * TE;

    if (lane < TE) sDst[lane] = edge_index[NEDGE + e0 + lane];
    __syncthreads();

    // ---- gather node rows ----
    {
        const float* nrow = node_attr + (size_t)sDst[m] * IRR;
        float* g = sG + m * SG_STRIDE;
        #pragma unroll
        for (int t = 0; t < 3; t++) {
            int c = quad + t * 4;
            *(float4*)(g + c * 4) = *(const float4*)(nrow + c * 4);
        }
        if (quad < 2) { int c = 12 + quad; *(float4*)(g + c * 4) = *(const float4*)(nrow + c * 4); }
    }

    // ---- GEMM1 transposed: lane holds H[e=m][hid] ----
    {
        const float* arow = edge_attr + (size_t)(e0 + m) * EF;
        float av0[8], av1[8];
        {
            float4 p0 = *(const float4*)(arow + quad * 8);
            float4 p1 = *(const float4*)(arow + quad * 8 + 4);
            av0[0]=p0.x; av0[1]=p0.y; av0[2]=p0.z; av0[3]=p0.w;
            av0[4]=p1.x; av0[5]=p1.y; av0[6]=p1.z; av0[7]=p1.w;
        }
        if (quad < 2) {
            float4 p0 = *(const float4*)(arow + 32 + quad * 8);
            float4 p1 = *(const float4*)(arow + 32 + quad * 8 + 4);
            av1[0]=p0.x; av1[1]=p0.y; av1[2]=p0.z; av1[3]=p0.w;
            av1[4]=p1.x; av1[5]=p1.y; av1[6]=p1.z; av1[7]=p1.w;
        } else {
            #pragma unroll
            for (int j = 0; j < 8; j++) av1[j] = 0.f;
            if (quad == 2) av1[0] = 1.f;           // bias row k=48
        }
        u16x8 ub0, ub1;
        #pragma unroll
        for (int j = 0; j < 8; j++) { ub0[j] = f2bf(av0[j]); ub1[j] = f2bf(av1[j]); }
        bf16x8 hb0 = __builtin_bit_cast(bf16x8, ub0);
        bf16x8 hb1 = __builtin_bit_cast(bf16x8, ub1);

        #pragma unroll
        for (int nth = 0; nth < 3; nth++) {
            bf16x8 a0 = __builtin_bit_cast(bf16x8, *(const u16x8*)&W1T[(nth*16 + m)*64 + quad*8]);
            bf16x8 a1 = __builtin_bit_cast(bf16x8, *(const u16x8*)&W1T[(nth*16 + m)*64 + 32 + quad*8]);
            f32x4 c = {0.f, 0.f, 0.f, 0.f};
            c = __builtin_amdgcn_mfma_f32_16x16x32_bf16(a0, hb0, c, 0, 0, 0);
            c = __builtin_amdgcn_mfma_f32_16x16x32_bf16(a1, hb1, c, 0, 0, 0);
            u16x4 hp;
            #pragma unroll
            for (int r = 0; r < 4; r++) hp[r] = f2bf(fmaxf(c[r], 0.f));
            *(u16x4*)&sH[m * SH_STRIDE + nth*16 + quad*4] = hp;
        }
        if (quad == 3) {
            u16x4 b = {0x3F80, 0, 0, 0}, z = {0, 0, 0, 0};
            *(u16x4*)&sH[m * SH_STRIDE + 48] = b;
            *(u16x4*)&sH[m * SH_STRIDE + 52] = z;
            *(u16x4*)&sH[m * SH_STRIDE + 56] = z;
            *(u16x4*)&sH[m * SH_STRIDE + 60] = z;
        }
    }
    __syncthreads();

    // ---- F features (quad0), fp16 stores; indices 0..119 fit stride exactly ----
    if (quad == 0) {
        const float* x = sG + m * SG_STRIDE;
        float4 sh4 = *(const float4*)&edge_sh[(size_t)(e0 + m) * 4];
        const float s0 = sh4.x, sx = sh4.y, sy = sh4.z, sz = sh4.w;
        unsigned short* F = sF + m * SF_STRIDE;
        const float c0S = s0 * A_SCAL;
        const float c0V = s0 * A_VEC;
        const float cD3 = INV_SQRT3 * A_SCAL;
        const float cC2 = INV_SQRT2 * A_VEC;
        #pragma unroll
        for (int u = 0; u < 16; u++) {
            float x0e = x[u], x0o = x[40 + u];
            F[u]       = f2h(x0e * c0S);
            F[20 + u]  = f2h(x0e * A_VEC);
            F[84 + u]  = f2h(x0o * A_VEC);
            F[104 + u] = f2h(x0o * c0S);
        }
        #pragma unroll
        for (int u = 0; u < 4; u++) {
            float a0 = x[16 + u*3], a1 = x[16 + u*3 + 1], a2 = x[16 + u*3 + 2]; // x1o
            float b0 = x[28 + u*3], b1 = x[28 + u*3 + 1], b2 = x[28 + u*3 + 2]; // x1e
            F[16 + u]  = f2h((a0*sx + a1*sy + a2*sz) * cD3);
            F[100 + u] = f2h((b0*sx + b1*sy + b2*sz) * cD3);
            F[48 + u*3 + 0] = f2h((b1*sz - b2*sy) * cC2);
            F[48 + u*3 + 1] = f2h((b2*sx - b0*sz) * cC2);
            F[48 + u*3 + 2] = f2h((b0*sy - b1*sx) * cC2);
            F[60 + u*3 + 0] = f2h((a1*sz - a2*sy) * cC2);
            F[60 + u*3 + 1] = f2h((a2*sx - a0*sz) * cC2);
            F[60 + u*3 + 2] = f2h((a0*sy - a1*sx) * cC2);
            F[36 + u*3 + 0] = f2h(a0 * c0V);  F[36 + u*3 + 1] = f2h(a1 * c0V);  F[36 + u*3 + 2] = f2h(a2 * c0V);
            F[72 + u*3 + 0] = f2h(b0 * c0V);  F[72 + u*3 + 1] = f2h(b1 * c0V);  F[72 + u*3 + 2] = f2h(b2 * c0V);
        }
        sS1[m][0] = sx; sS1[m][1] = sy; sS1[m][2] = sz;
    }
    __syncthreads();

    bf16x8 HB0 = __builtin_bit_cast(bf16x8, *(const u16x8*)&sH[m * SH_STRIDE + quad*8]);
    bf16x8 HB1 = __builtin_bit_cast(bf16x8, *(const u16x8*)&sH[m * SH_STRIDE + 32 + quad*8]);

    // ---- fused GEMM2 + consume, fully unrolled, depth-2 prefetch ----
    float oe[4]  = {0.f,0.f,0.f,0.f};
    float oo[4]  = {0.f,0.f,0.f,0.f};
    float sA[4]  = {0.f,0.f,0.f,0.f};
    float sD[4]  = {0.f,0.f,0.f,0.f};
    float t1o[12] = {0.f,0.f,0.f,0.f,0.f,0.f,0.f,0.f,0.f,0.f,0.f,0.f};
    float t1e[12] = {0.f,0.f,0.f,0.f,0.f,0.f,0.f,0.f,0.f,0.f,0.f,0.f};

    const unsigned short* Fm = sF + m * SF_STRIDE;
    const unsigned short* Wb = W2T + m * 64 + quad * 8;

    u16x8 wa[2], wb[2];
    wa[0] = *(const u16x8*)(Wb + 0 * 1024);
    wb[0] = *(const u16x8*)(Wb + 0 * 1024 + 32);
    wa[1] = *(const u16x8*)(Wb + 1 * 1024);
    wb[1] = *(const u16x8*)(Wb + 1 * 1024 + 32);

    #pragma unroll
    for (int nt = 0; nt < 52; nt++) {
        const int b = nt & 1;
        f32x4 c = {0.f, 0.f, 0.f, 0.f};
        c = __builtin_amdgcn_mfma_f32_16x16x32_bf16(__builtin_bit_cast(bf16x8, wa[b]), HB0, c, 0, 0, 0);
        c = __builtin_amdgcn_mfma_f32_16x16x32_bf16(__builtin_bit_cast(bf16x8, wb[b]), HB1, c, 0, 0, 0);
        if (nt + 2 < 52) {
            wa[b] = *(const u16x8*)(Wb + (nt + 2) * 1024);
            wb[b] = *(const u16x8*)(Wb + (nt + 2) * 1024 + 32);
        }
        if (nt < 20) {                          // o0e
            float f = h2f(Fm[nt]);
            #pragma unroll
            for (int r = 0; r < 4; r++) oe[r] += f * c[r];
        } else if (nt < 24) {                   // wA1 dot
            float f = h2f(Fm[20 + (nt - 20)*4 + quad]);
            #pragma unroll
            for (int r = 0; r < 4; r++) sA[r] += f * c[r];
        } else if (nt < 26) {                   // wB1+wC1
            int u = (nt - 24)*4 + quad;
            #pragma unroll
            for (int i = 0; i < 3; i++) {
                float f = h2f(Fm[36 + u*3 + i]);
                #pragma unroll
                for (int r = 0; r < 4; r++) t1o[i*4 + r] += f * c[r];
            }
        } else if (nt < 28) {                   // wB1e+wC1e
            int j = (nt - 26)*4 + quad;
            #pragma unroll
            for (int i = 0; i < 3; i++) {
                float f = h2f(Fm[60 + j*3 + i]);
                #pragma unroll
                for (int r = 0; r < 4; r++) t1e[i*4 + r] += f * c[r];
            }
        } else if (nt < 32) {                   // wD1e dot
            float f = h2f(Fm[84 + (nt - 28)*4 + quad]);
            #pragma unroll
            for (int r = 0; r < 4; r++) sD[r] += f * c[r];
        } else {                                // o0o
            float f = h2f(Fm[68 + nt]);
            #pragma unroll
            for (int r = 0; r < 4; r++) oo[r] += f * c[r];
        }
    }

    // ---- cross-quad butterfly ----
    #pragma unroll
    for (int r = 0; r < 4; r++) {
        sA[r] += __shfl_xor(sA[r], 16, 64);  sA[r] += __shfl_xor(sA[r], 32, 64);
        sD[r] += __shfl_xor(sD[r], 16, 64);  sD[r] += __shfl_xor(sD[r], 32, 64);
    }
    #pragma unroll
    for (int i = 0; i < 12; i++) {
        t1o[i] += __shfl_xor(t1o[i], 16, 64);  t1o[i] += __shfl_xor(t1o[i], 32, 64);
        t1e[i] += __shfl_xor(t1e[i], 16, 64);  t1e[i] += __shfl_xor(t1e[i], 32, 64);
    }

    __syncthreads();                           // all sF reads complete before sO overlay writes

    float* sO = (float*)sF;                    // stride 60 floats = 240B rows; all f4 stores 16B-aligned
    {
        float4 v0; v0.x = oe[0]; v0.y = oe[1]; v0.z = oe[2]; v0.w = oe[3];
        float4 v1; v1.x = oo[0]; v1.y = oo[1]; v1.z = oo[2]; v1.w = oo[3];
        *(float4*)&sO[m * 60 + quad*4]      = v0;   // channels 0..15
        *(float4*)&sO[m * 60 + 40 + quad*4] = v1;   // channels 40..55
    }
    if (quad == 0) {
        float s1x = sS1[m][0], s1y = sS1[m][1], s1z = sS1[m][2];
        #pragma unroll
        for (int r = 0; r < 4; r++) {
            sO[m * 60 + 16 + r*3 + 0] = sA[r] * s1x + t1o[0*4 + r];
            sO[m * 60 + 16 + r*3 + 1] = sA[r] * s1y + t1o[1*4 + r];
            sO[m * 60 + 16 + r*3 + 2] = sA[r] * s1z + t1o[2*4 + r];
        }
    } else if (quad == 1) {
        float s1x = sS1[m][0], s1y = sS1[m][1], s1z = sS1[m][2];
        #pragma unroll
        for (int r = 0; r < 4; r++) {
            sO[m * 60 + 28 + r*3 + 0] = sD[r] * s1x + t1e[0*4 + r];
            sO[m * 60 + 28 + r*3 + 1] = sD[r] * s1y + t1e[1*4 + r];
            sO[m * 60 + 28 + r*3 + 2] = sD[r] * s1z + t1e[2*4 + r];
        }
    }
    __syncthreads();

    // ---- plain coalesced bf16 row stores (no atomics) ----
    unsigned* tp32 = (unsigned*)tpB;
    #pragma unroll
    for (int it = 0; it < 7; it++) {
        int idx = it * 64 + lane;          // 0..447 ; 28 dwords per edge
        int e = idx / 28, chp = idx - e * 28;
        float lo = sO[e * 60 + chp*2];
        float hi = sO[e * 60 + chp*2 + 1];
        unsigned pk = ((unsigned)f2bf(hi) << 16) | (unsigned)f2bf(lo);
        tp32[(size_t)(e0 + e) * 28 + chp] = pk;
    }
}

// ---- per-node gather-reduce + divide: half-wave per node, depth-2 prefetch ----
__global__ __launch_bounds__(256) void k_reduce(
    const unsigned short* __restrict__ tpB,
    const int* __restrict__ hist, const int* __restrict__ offs,
    const int* __restrict__ eid, float* __restrict__ out)
{
    const int col = threadIdx.x & 31;
    const int n   = blockIdx.x * 8 + (threadIdx.x >> 5);   // 1000 blocks -> 8000 nodes

    if (col >= 28) return;
    const int cnt = hist[n];
    const int beg = offs[n];
    const unsigned* tp32 = (const unsigned*)tpB;

    unsigned c0 = 0, c1 = 0;
    if (cnt > 0) c0 = tp32[(size_t)eid[beg] * 28 + col];
    if (cnt > 1) c1 = tp32[(size_t)eid[beg + 1] * 28 + col];

    float ax = 0.f, ay = 0.f;
    for (int i = 0; i < cnt; i++) {
        unsigned nxt = 0;
        if (i + 2 < cnt) nxt = tp32[(size_t)eid[beg + i + 2] * 28 + col];
        ax += __builtin_bit_cast(float, c0 << 16);
        ay += __builtin_bit_cast(float, c0 & 0xFFFF0000u);
        c0 = c1; c1 = nxt;
    }
    float inv = 1.f / fmaxf((float)cnt, 1.f);
    float2 o; o.x = ax * inv; o.y = ay * inv;
    *(float2*)&out[(size_t)n * IRR + col * 2] = o;
}

extern "C" void kernel_launch(void* const* d_in, const int* in_sizes, int n_in,
                              void* d_out, int out_size, void* d_ws, size_t ws_size,
                              hipStream_t stream) {
    const float* node_attr  = (const float*)d_in[0];
    const float* edge_attr  = (const float*)d_in[1];
    const float* edge_sh    = (const float*)d_in[2];
    const float* fc_w1      = (const float*)d_in[3];
    const float* fc_b1      = (const float*)d_in[4];
    const float* fc_w2      = (const float*)d_in[5];
    const float* fc_b2      = (const float*)d_in[6];
    const int*   edge_index = (const int*)d_in[7];

    int* hist   = (int*)d_ws;                       // 8000
    int* offs   = hist + NNODE;                     // 8000
    int* cursor = offs + NNODE;                     // 8000
    int* eid    = cursor + NNODE;                   // 160000
    unsigned short* W1T = (unsigned short*)(eid + NEDGE);     // 48*64
    unsigned short* W2T = W1T + 48 * 64;                      // 832*64
    unsigned short* tpB = W2T + (size_t)WN * 64;              // 160000*56 bf16

    k_setup<<<(EF * WN + WN * 16 + 255) / 256, 256, 0, stream>>>(
        fc_w1, fc_b1, fc_w2, fc_b2, W1T, W2T, hist);
    k_hist<<<NEDGE / 256, 256, 0, stream>>>(edge_index, hist);
    k_scan<<<1, 1024, 0, stream>>>(hist, offs, cursor);
    k_fill<<<NEDGE / 256, 256, 0, stream>>>(edge_index, cursor, eid);

    tp_fused<<<NBLK, NT, 0, stream>>>(node_attr, edge_attr, edge_sh, edge_index,
                                      W1T, W2T, tpB);

    k_reduce<<<NNODE / 8, 256, 0, stream>>>(tpB, hist, offs, eid, (float*)d_out);
}

// Round 8
// 263.173 us; speedup vs baseline: 1.0938x; 1.0938x over previous
//
#include <hip/hip_runtime.h>
#include <hip/hip_fp16.h>

#define IRR    56
#define EF     48
#define WN     832
#define NEDGE  160000
#define NNODE  8000
#define TE     16          // edges per wave (= per block)
#define NT     64
#define NBLK   (NEDGE / TE)

#define SG_STRIDE 60       // floats (gather tile)
#define SH_STRIDE 72       // ushorts
#define SF_STRIDE 120      // ushorts (fp16 F, exactly 120 entries); sO overlays at stride 60 f32 (16B-aligned rows)

#define INV_SQRT3 0.5773502691896258f
#define INV_SQRT2 0.7071067811865476f
#define A_SCAL    0.22360679774997896f   // 1/sqrt(20)
#define A_VEC     0.20412414523193154f   // 1/sqrt(24)

typedef __bf16 bf16x8 __attribute__((ext_vector_type(8)));
typedef float  f32x4  __attribute__((ext_vector_type(4)));
typedef unsigned short u16x8 __attribute__((ext_vector_type(8)));
typedef unsigned short u16x4 __attribute__((ext_vector_type(4)));

__device__ __forceinline__ unsigned short f2bf(float f) {
    unsigned int u = __builtin_bit_cast(unsigned int, f);
    u += 0x7FFFu + ((u >> 16) & 1u);          // RNE
    return (unsigned short)(u >> 16);
}
__device__ __forceinline__ unsigned short f2h(float f) {
    __half h = __float2half(f);
    return __builtin_bit_cast(unsigned short, h);
}
__device__ __forceinline__ float h2f(unsigned short u) {
    __half h = __builtin_bit_cast(__half, u);
    return __half2float(h);
}

// ---- setup: zero hist + build bf16 transposed weight tables [n][64] (coalesced reads) ----
__global__ void k_setup(const float* __restrict__ w1, const float* __restrict__ b1,
                        const float* __restrict__ w2, const float* __restrict__ b2,
                        unsigned short* __restrict__ W1T, unsigned short* __restrict__ W2T,
                        int* __restrict__ hist)
{
    int i = blockIdx.x * 256 + threadIdx.x;
    if (i < NNODE) hist[i] = 0;
    if (i < EF * WN) { int k = i / WN, n = i - k * WN; W2T[n * 64 + k] = f2bf(w2[i]); }
    if (i < WN * 16) { int n = i >> 4, kk = EF + (i & 15); W2T[n * 64 + kk] = (kk == EF) ? f2bf(b2[n]) : (unsigned short)0; }
    if (i < EF * EF) { int k = i / EF, n = i - k * EF; W1T[n * 64 + k] = f2bf(w1[i]); }
    if (i < EF * 16) { int n = i >> 4, kk = EF + (i & 15); W1T[n * 64 + kk] = (kk == EF) ? f2bf(b1[n]) : (unsigned short)0; }
}

__global__ void k_hist(const int* __restrict__ edge_index, int* __restrict__ hist)
{
    int e = blockIdx.x * 256 + threadIdx.x;
    if (e < NEDGE) atomicAdd(&hist[edge_index[e]], 1);
}

// single-block exclusive scan of hist[8000] -> offs, cursor (shfl-based)
__global__ __launch_bounds__(1024) void k_scan(const int* __restrict__ hist,
                                               int* __restrict__ offs, int* __restrict__ cursor)
{
    __shared__ int wpart[16];
    const int t = threadIdx.x;
    const int lane = t & 63;
    const int w = t >> 6;
    const int base = t * 8;
    int v[8]; int tot = 0;
    #pragma unroll
    for (int j = 0; j < 8; j++) {
        int x = (base + j < NNODE) ? hist[base + j] : 0;
        v[j] = tot; tot += x;
    }
    int s = tot;
    #pragma unroll
    for (int d = 1; d < 64; d <<= 1) {
        int up = __shfl_up(s, d, 64);
        if (lane >= d) s += up;
    }
    if (lane == 63) wpart[w] = s;
    int texcl = s - tot;
    __syncthreads();
    if (t < 16) {
        int x = wpart[t];
        #pragma unroll
        for (int d = 1; d < 16; d <<= 1) {
            int up = __shfl_up(x, d, 64);
            if (lane >= d) x += up;
        }
        wpart[t] = x;
    }
    __syncthreads();
    int woff = (w > 0) ? wpart[w - 1] : 0;
    int boff = woff + texcl;
    #pragma unroll
    for (int j = 0; j < 8; j++) {
        if (base + j < NNODE) { int o = boff + v[j]; offs[base + j] = o; cursor[base + j] = o; }
    }
}

// fill: perm[e] = CSR slot for edge e (tp_fused stores rows pre-sorted by src node)
__global__ void k_fill(const int* __restrict__ edge_index,
                       int* __restrict__ cursor, int* __restrict__ perm)
{
    int e = blockIdx.x * 256 + threadIdx.x;
    if (e < NEDGE) {
        int pos = atomicAdd(&cursor[edge_index[e]], 1);
        perm[e] = pos;
    }
}

__global__ __launch_bounds__(NT) void tp_fused(
    const float* __restrict__ node_attr,
    const float* __restrict__ edge_attr,
    const float* __restrict__ edge_sh,
    const int*   __restrict__ edge_index,
    const int*   __restrict__ perm,
    const unsigned short* __restrict__ W1T,
    const unsigned short* __restrict__ W2T,
    unsigned short* __restrict__ tpB)
{
    __shared__ __align__(16) float sG[TE * SG_STRIDE];           // 3840B gather (dead after F-phase)
    __shared__ __align__(16) unsigned short sH[TE * SH_STRIDE];  // 2304B H^T
    __shared__ __align__(16) unsigned short sF[TE * SF_STRIDE];  // 3840B fp16 F; sO overlays (stride 60 f32, 16B-aligned)
    __shared__ float sS1[TE][4];
    __shared__ int   sDst[TE];
    __shared__ int   sSlot[TE];

    const int lane = threadIdx.x;
    const int m    = lane & 15;
    const int quad = lane >> 4;
    const int e0   = blockIdx.x * TE;

    if (lane < TE)          sDst[lane]        = edge_index[NEDGE + e0 + lane];
    else if (lane < 2*TE)   sSlot[lane - TE]  = perm[e0 + lane - TE];
    __syncthreads();

    // ---- gather node rows ----
    {
        const float* nrow = node_attr + (size_t)sDst[m] * IRR;
        float* g = sG + m * SG_STRIDE;
        #pragma unroll
        for (int t = 0; t < 3; t++) {
            int c = quad + t * 4;
            *(float4*)(g + c * 4) = *(const float4*)(nrow + c * 4);
        }
        if (quad < 2) { int c = 12 + quad; *(float4*)(g + c * 4) = *(const float4*)(nrow + c * 4); }
    }

    // ---- GEMM1 transposed: lane holds H[e=m][hid] ----
    {
        const float* arow = edge_attr + (size_t)(e0 + m) * EF;
        float av0[8], av1[8];
        {
            float4 p0 = *(const float4*)(arow + quad * 8);
            float4 p1 = *(const float4*)(arow + quad * 8 + 4);
            av0[0]=p0.x; av0[1]=p0.y; av0[2]=p0.z; av0[3]=p0.w;
            av0[4]=p1.x; av0[5]=p1.y; av0[6]=p1.z; av0[7]=p1.w;
        }
        if (quad < 2) {
            float4 p0 = *(const float4*)(arow + 32 + quad * 8);
            float4 p1 = *(const float4*)(arow + 32 + quad * 8 + 4);
            av1[0]=p0.x; av1[1]=p0.y; av1[2]=p0.z; av1[3]=p0.w;
            av1[4]=p1.x; av1[5]=p1.y; av1[6]=p1.z; av1[7]=p1.w;
        } else {
            #pragma unroll
            for (int j = 0; j < 8; j++) av1[j] = 0.f;
            if (quad == 2) av1[0] = 1.f;           // bias row k=48
        }
        u16x8 ub0, ub1;
        #pragma unroll
        for (int j = 0; j < 8; j++) { ub0[j] = f2bf(av0[j]); ub1[j] = f2bf(av1[j]); }
        bf16x8 hb0 = __builtin_bit_cast(bf16x8, ub0);
        bf16x8 hb1 = __builtin_bit_cast(bf16x8, ub1);

        #pragma unroll
        for (int nth = 0; nth < 3; nth++) {
            bf16x8 a0 = __builtin_bit_cast(bf16x8, *(const u16x8*)&W1T[(nth*16 + m)*64 + quad*8]);
            bf16x8 a1 = __builtin_bit_cast(bf16x8, *(const u16x8*)&W1T[(nth*16 + m)*64 + 32 + quad*8]);
            f32x4 c = {0.f, 0.f, 0.f, 0.f};
            c = __builtin_amdgcn_mfma_f32_16x16x32_bf16(a0, hb0, c, 0, 0, 0);
            c = __builtin_amdgcn_mfma_f32_16x16x32_bf16(a1, hb1, c, 0, 0, 0);
            u16x4 hp;
            #pragma unroll
            for (int r = 0; r < 4; r++) hp[r] = f2bf(fmaxf(c[r], 0.f));
            *(u16x4*)&sH[m * SH_STRIDE + nth*16 + quad*4] = hp;
        }
        if (quad == 3) {
            u16x4 b = {0x3F80, 0, 0, 0}, z = {0, 0, 0, 0};
            *(u16x4*)&sH[m * SH_STRIDE + 48] = b;
            *(u16x4*)&sH[m * SH_STRIDE + 52] = z;
            *(u16x4*)&sH[m * SH_STRIDE + 56] = z;
            *(u16x4*)&sH[m * SH_STRIDE + 60] = z;
        }
    }
    __syncthreads();

    // ---- F features (quad0), fp16 stores ----
    if (quad == 0) {
        const float* x = sG + m * SG_STRIDE;
        float4 sh4 = *(const float4*)&edge_sh[(size_t)(e0 + m) * 4];
        const float s0 = sh4.x, sx = sh4.y, sy = sh4.z, sz = sh4.w;
        unsigned short* F = sF + m * SF_STRIDE;
        const float c0S = s0 * A_SCAL;
        const float c0V = s0 * A_VEC;
        const float cD3 = INV_SQRT3 * A_SCAL;
        const float cC2 = INV_SQRT2 * A_VEC;
        #pragma unroll
        for (int u = 0; u < 16; u++) {
            float x0e = x[u], x0o = x[40 + u];
            F[u]       = f2h(x0e * c0S);
            F[20 + u]  = f2h(x0e * A_VEC);
            F[84 + u]  = f2h(x0o * A_VEC);
            F[104 + u] = f2h(x0o * c0S);
        }
        #pragma unroll
        for (int u = 0; u < 4; u++) {
            float a0 = x[16 + u*3], a1 = x[16 + u*3 + 1], a2 = x[16 + u*3 + 2]; // x1o
            float b0 = x[28 + u*3], b1 = x[28 + u*3 + 1], b2 = x[28 + u*3 + 2]; // x1e
            F[16 + u]  = f2h((a0*sx + a1*sy + a2*sz) * cD3);
            F[100 + u] = f2h((b0*sx + b1*sy + b2*sz) * cD3);
            F[48 + u*3 + 0] = f2h((b1*sz - b2*sy) * cC2);
            F[48 + u*3 + 1] = f2h((b2*sx - b0*sz) * cC2);
            F[48 + u*3 + 2] = f2h((b0*sy - b1*sx) * cC2);
            F[60 + u*3 + 0] = f2h((a1*sz - a2*sy) * cC2);
            F[60 + u*3 + 1] = f2h((a2*sx - a0*sz) * cC2);
            F[60 + u*3 + 2] = f2h((a0*sy - a1*sx) * cC2);
            F[36 + u*3 + 0] = f2h(a0 * c0V);  F[36 + u*3 + 1] = f2h(a1 * c0V);  F[36 + u*3 + 2] = f2h(a2 * c0V);
            F[72 + u*3 + 0] = f2h(b0 * c0V);  F[72 + u*3 + 1] = f2h(b1 * c0V);  F[72 + u*3 + 2] = f2h(b2 * c0V);
        }
        sS1[m][0] = sx; sS1[m][1] = sy; sS1[m][2] = sz;
    }
    __syncthreads();

    bf16x8 HB0 = __builtin_bit_cast(bf16x8, *(const u16x8*)&sH[m * SH_STRIDE + quad*8]);
    bf16x8 HB1 = __builtin_bit_cast(bf16x8, *(const u16x8*)&sH[m * SH_STRIDE + 32 + quad*8]);

    // ---- fused GEMM2 + consume: rolled loop, depth-4 ping-pong prefetch (static slots) ----
    float oe[4]  = {0.f,0.f,0.f,0.f};
    float oo[4]  = {0.f,0.f,0.f,0.f};
    float sA[4]  = {0.f,0.f,0.f,0.f};
    float sD[4]  = {0.f,0.f,0.f,0.f};
    float t1o[12] = {0.f,0.f,0.f,0.f,0.f,0.f,0.f,0.f,0.f,0.f,0.f,0.f};
    float t1e[12] = {0.f,0.f,0.f,0.f,0.f,0.f,0.f,0.f,0.f,0.f,0.f,0.f};

    const unsigned short* Fm = sF + m * SF_STRIDE;
    const unsigned short* Wb = W2T + m * 64 + quad * 8;

    auto consume = [&](int nt, f32x4 c) {
        if (nt < 20) {                          // o0e
            float f = h2f(Fm[nt]);
            #pragma unroll
            for (int r = 0; r < 4; r++) oe[r] += f * c[r];
        } else if (nt < 24) {                   // wA1 dot
            float f = h2f(Fm[20 + (nt - 20)*4 + quad]);
            #pragma unroll
            for (int r = 0; r < 4; r++) sA[r] += f * c[r];
        } else if (nt < 26) {                   // wB1+wC1
            int u = (nt - 24)*4 + quad;
            #pragma unroll
            for (int i = 0; i < 3; i++) {
                float f = h2f(Fm[36 + u*3 + i]);
                #pragma unroll
                for (int r = 0; r < 4; r++) t1o[i*4 + r] += f * c[r];
            }
        } else if (nt < 28) {                   // wB1e+wC1e
            int j = (nt - 26)*4 + quad;
            #pragma unroll
            for (int i = 0; i < 3; i++) {
                float f = h2f(Fm[60 + j*3 + i]);
                #pragma unroll
                for (int r = 0; r < 4; r++) t1e[i*4 + r] += f * c[r];
            }
        } else if (nt < 32) {                   // wD1e dot
            float f = h2f(Fm[84 + (nt - 28)*4 + quad]);
            #pragma unroll
            for (int r = 0; r < 4; r++) sD[r] += f * c[r];
        } else {                                // o0o
            float f = h2f(Fm[68 + nt]);
            #pragma unroll
            for (int r = 0; r < 4; r++) oo[r] += f * c[r];
        }
    };

    u16x8 A0 = *(const u16x8*)(Wb + 0*1024), B0 = *(const u16x8*)(Wb + 0*1024 + 32);
    u16x8 A1 = *(const u16x8*)(Wb + 1*1024), B1 = *(const u16x8*)(Wb + 1*1024 + 32);
    u16x8 A2 = *(const u16x8*)(Wb + 2*1024), B2 = *(const u16x8*)(Wb + 2*1024 + 32);
    u16x8 A3 = *(const u16x8*)(Wb + 3*1024), B3 = *(const u16x8*)(Wb + 3*1024 + 32);

    #pragma unroll 1
    for (int base = 0; base < 52; base += 4) {
        const bool pf = (base < 48);
        {
            f32x4 c = {0.f,0.f,0.f,0.f};
            c = __builtin_amdgcn_mfma_f32_16x16x32_bf16(__builtin_bit_cast(bf16x8, A0), HB0, c, 0, 0, 0);
            c = __builtin_amdgcn_mfma_f32_16x16x32_bf16(__builtin_bit_cast(bf16x8, B0), HB1, c, 0, 0, 0);
            if (pf) { A0 = *(const u16x8*)(Wb + (base+4)*1024); B0 = *(const u16x8*)(Wb + (base+4)*1024 + 32); }
            consume(base + 0, c);
        }
        {
            f32x4 c = {0.f,0.f,0.f,0.f};
            c = __builtin_amdgcn_mfma_f32_16x16x32_bf16(__builtin_bit_cast(bf16x8, A1), HB0, c, 0, 0, 0);
            c = __builtin_amdgcn_mfma_f32_16x16x32_bf16(__builtin_bit_cast(bf16x8, B1), HB1, c, 0, 0, 0);
            if (pf) { A1 = *(const u16x8*)(Wb + (base+5)*1024); B1 = *(const u16x8*)(Wb + (base+5)*1024 + 32); }
            consume(base + 1, c);
        }
        {
            f32x4 c = {0.f,0.f,0.f,0.f};
            c = __builtin_amdgcn_mfma_f32_16x16x32_bf16(__builtin_bit_cast(bf16x8, A2), HB0, c, 0, 0, 0);
            c = __builtin_amdgcn_mfma_f32_16x16x32_bf16(__builtin_bit_cast(bf16x8, B2), HB1, c, 0, 0, 0);
            if (pf) { A2 = *(const u16x8*)(Wb + (base+6)*1024); B2 = *(const u16x8*)(Wb + (base+6)*1024 + 32); }
            consume(base + 2, c);
        }
        {
            f32x4 c = {0.f,0.f,0.f,0.f};
            c = __builtin_amdgcn_mfma_f32_16x16x32_bf16(__builtin_bit_cast(bf16x8, A3), HB0, c, 0, 0, 0);
            c = __builtin_amdgcn_mfma_f32_16x16x32_bf16(__builtin_bit_cast(bf16x8, B3), HB1, c, 0, 0, 0);
            if (pf) { A3 = *(const u16x8*)(Wb + (base+7)*1024); B3 = *(const u16x8*)(Wb + (base+7)*1024 + 32); }
            consume(base + 3, c);
        }
    }

    // ---- cross-quad butterfly (o1o/o1e paths) ----
    #pragma unroll
    for (int r = 0; r < 4; r++) {
        sA[r] += __shfl_xor(sA[r], 16, 64);  sA[r] += __shfl_xor(sA[r], 32, 64);
        sD[r] += __shfl_xor(sD[r], 16, 64);  sD[r] += __shfl_xor(sD[r], 32, 64);
    }
    #pragma unroll
    for (int i = 0; i < 12; i++) {
        t1o[i] += __shfl_xor(t1o[i], 16, 64);  t1o[i] += __shfl_xor(t1o[i], 32, 64);
        t1e[i] += __shfl_xor(t1e[i], 16, 64);  t1e[i] += __shfl_xor(t1e[i], 32, 64);
    }

    __syncthreads();                           // all sF reads complete before sO overlay writes

    float* sO = (float*)sF;                    // stride 60 floats = 240B rows; f4 stores 16B-aligned
    {
        float4 v0; v0.x = oe[0]; v0.y = oe[1]; v0.z = oe[2]; v0.w = oe[3];
        float4 v1; v1.x = oo[0]; v1.y = oo[1]; v1.z = oo[2]; v1.w = oo[3];
        *(float4*)&sO[m * 60 + quad*4]      = v0;   // channels 0..15
        *(float4*)&sO[m * 60 + 40 + quad*4] = v1;   // channels 40..55
    }
    if (quad == 0) {
        float s1x = sS1[m][0], s1y = sS1[m][1], s1z = sS1[m][2];
        #pragma unroll
        for (int r = 0; r < 4; r++) {
            sO[m * 60 + 16 + r*3 + 0] = sA[r] * s1x + t1o[0*4 + r];
            sO[m * 60 + 16 + r*3 + 1] = sA[r] * s1y + t1o[1*4 + r];
            sO[m * 60 + 16 + r*3 + 2] = sA[r] * s1z + t1o[2*4 + r];
        }
    } else if (quad == 1) {
        float s1x = sS1[m][0], s1y = sS1[m][1], s1z = sS1[m][2];
        #pragma unroll
        for (int r = 0; r < 4; r++) {
            sO[m * 60 + 28 + r*3 + 0] = sD[r] * s1x + t1e[0*4 + r];
            sO[m * 60 + 28 + r*3 + 1] = sD[r] * s1y + t1e[1*4 + r];
            sO[m * 60 + 28 + r*3 + 2] = sD[r] * s1z + t1e[2*4 + r];
        }
    }
    __syncthreads();

    // ---- bf16 row stores, pre-sorted by src node via perm (no atomics) ----
    unsigned* tp32 = (unsigned*)tpB;
    #pragma unroll
    for (int it = 0; it < 7; it++) {
        int idx = it * 64 + lane;          // 0..447 ; 28 dwords per edge
        int e = idx / 28, chp = idx - e * 28;
        float lo = sO[e * 60 + chp*2];
        float hi = sO[e * 60 + chp*2 + 1];
        unsigned pk = ((unsigned)f2bf(hi) << 16) | (unsigned)f2bf(lo);
        tp32[(size_t)sSlot[e] * 28 + chp] = pk;
    }
}

// ---- per-node reduce + divide: contiguous CSR rows, half-wave per node ----
__global__ __launch_bounds__(256) void k_reduce(
    const unsigned short* __restrict__ tpB,
    const int* __restrict__ hist, const int* __restrict__ offs,
    float* __restrict__ out)
{
    const int col = threadIdx.x & 31;
    const int n   = blockIdx.x * 8 + (threadIdx.x >> 5);   // 1000 blocks -> 8000 nodes

    if (col >= 28) return;
    const int cnt = hist[n];
    const int beg = offs[n];
    const unsigned* p = (const unsigned*)tpB + (size_t)beg * 28 + col;

    unsigned c0 = 0, c1 = 0;
    if (cnt > 0) c0 = p[0];
    if (cnt > 1) c1 = p[28];

    float ax = 0.f, ay = 0.f;
    for (int i = 0; i < cnt; i++) {
        unsigned nxt = 0;
        if (i + 2 < cnt) nxt = p[(i + 2) * 28];
        ax += __builtin_bit_cast(float, c0 << 16);
        ay += __builtin_bit_cast(float, c0 & 0xFFFF0000u);
        c0 = c1; c1 = nxt;
    }
    float inv = 1.f / fmaxf((float)cnt, 1.f);
    float2 o; o.x = ax * inv; o.y = ay * inv;
    *(float2*)&out[(size_t)n * IRR + col * 2] = o;
}

extern "C" void kernel_launch(void* const* d_in, const int* in_sizes, int n_in,
                              void* d_out, int out_size, void* d_ws, size_t ws_size,
                              hipStream_t stream) {
    const float* node_attr  = (const float*)d_in[0];
    const float* edge_attr  = (const float*)d_in[1];
    const float* edge_sh    = (const float*)d_in[2];
    const float* fc_w1      = (const float*)d_in[3];
    const float* fc_b1      = (const float*)d_in[4];
    const float* fc_w2      = (const float*)d_in[5];
    const float* fc_b2      = (const float*)d_in[6];
    const int*   edge_index = (const int*)d_in[7];

    int* hist   = (int*)d_ws;                       // 8000
    int* offs   = hist + NNODE;                     // 8000
    int* cursor = offs + NNODE;                     // 8000
    int* perm   = cursor + NNODE;                   // 160000
    unsigned short* W1T = (unsigned short*)(perm + NEDGE);    // 48*64
    unsigned short* W2T = W1T + 48 * 64;                      // 832*64
    unsigned short* tpB = W2T + (size_t)WN * 64;              // 160000*56 bf16

    k_setup<<<(EF * WN + WN * 16 + 255) / 256, 256, 0, stream>>>(
        fc_w1, fc_b1, fc_w2, fc_b2, W1T, W2T, hist);
    k_hist<<<NEDGE / 256, 256, 0, stream>>>(edge_index, hist);
    k_scan<<<1, 1024, 0, stream>>>(hist, offs, cursor);
    k_fill<<<NEDGE / 256, 256, 0, stream>>>(edge_index, cursor, perm);

    tp_fused<<<NBLK, NT, 0, stream>>>(node_attr, edge_attr, edge_sh, edge_index,
                                      perm, W1T, W2T, tpB);

    k_reduce<<<NNODE / 8, 256, 0, stream>>>(tpB, hist, offs, (float*)d_out);
}

// Round 9
// 192.441 us; speedup vs baseline: 1.4958x; 1.3676x over previous
//
#include <hip/hip_runtime.h>
#include <hip/hip_fp16.h>

#define IRR    56
#define EF     48
#define WN     832
#define NEDGE  160000
#define NNODE  8000
#define NT     256         // 4 waves, 64 edges per block
#define EB     64          // edges per block
#define NBLK   (NEDGE / EB)
#define NPASS  4
#define TPP    13          // W2 n-tiles per pass (52 total)
#define SW2_U16 (TPP * 2 * 64 * 8)   // 13312 ushorts = 26624 B per pass

#define SG_STRIDE 60       // floats per edge row (gather; overlays sW2)
#define SH_STRIDE 72       // ushorts
#define SF_STRIDE 120      // ushorts (fp16 F); sO overlays at 60 f32 (240B rows, 16B-aligned)

#define INV_SQRT3 0.5773502691896258f
#define INV_SQRT2 0.7071067811865476f
#define A_SCAL    0.22360679774997896f   // 1/sqrt(20)
#define A_VEC     0.20412414523193154f   // 1/sqrt(24)

typedef __bf16 bf16x8 __attribute__((ext_vector_type(8)));
typedef float  f32x4  __attribute__((ext_vector_type(4)));
typedef unsigned short u16x8 __attribute__((ext_vector_type(8)));
typedef unsigned short u16x4 __attribute__((ext_vector_type(4)));

__device__ __forceinline__ unsigned short f2bf(float f) {
    unsigned int u = __builtin_bit_cast(unsigned int, f);
    u += 0x7FFFu + ((u >> 16) & 1u);          // RNE
    return (unsigned short)(u >> 16);
}
__device__ __forceinline__ unsigned short f2h(float f) {
    __half h = __float2half(f);
    return __builtin_bit_cast(unsigned short, h);
}
__device__ __forceinline__ float h2f(unsigned short u) {
    __half h = __builtin_bit_cast(__half, u);
    return __half2float(h);
}

// ---- setup: zero accum/counts + W1T [n][64] + W2L lane-major fragment layout ----
// W2L[o]: o = ((i*2+f)*64 + l)*8 + j ; lane l=(q*16+m); value = W2[k= f*32+q*8+j][n= i*16+m]
__global__ void k_setup(const float* __restrict__ w1, const float* __restrict__ b1,
                        const float* __restrict__ w2, const float* __restrict__ b2,
                        unsigned short* __restrict__ W1T, unsigned short* __restrict__ W2L,
                        float* __restrict__ accum_counts)
{
    int o = blockIdx.x * 256 + threadIdx.x;
    if (o < NNODE * IRR + NNODE) accum_counts[o] = 0.f;
    if (o < 52 * 2 * 64 * 8) {
        int i = o >> 10;
        int rem = o & 1023;
        int f = rem >> 9;
        int rem2 = rem & 511;
        int l = rem2 >> 3, j = rem2 & 7;
        int mm = l & 15, qq = l >> 4;
        int k = f * 32 + qq * 8 + j;
        int n = i * 16 + mm;
        float v = (k < EF) ? w2[k * WN + n] : ((k == EF) ? b2[n] : 0.f);
        W2L[o] = f2bf(v);
    }
    if (o < EF * EF) { int k = o / EF, n = o - k * EF; W1T[n * 64 + k] = f2bf(w1[o]); }
    if (o < EF * 16) { int n = o >> 4, kk = EF + (o & 15); W1T[n * 64 + kk] = (kk == EF) ? f2bf(b1[n]) : (unsigned short)0; }
}

__global__ __launch_bounds__(NT) void tp_fused(
    const float* __restrict__ node_attr,
    const float* __restrict__ edge_attr,
    const float* __restrict__ edge_sh,
    const int*   __restrict__ edge_index,
    const unsigned short* __restrict__ W1T,
    const unsigned short* __restrict__ W2L,
    float* __restrict__ accum,
    float* __restrict__ counts)
{
    __shared__ __align__(16) unsigned short sW2[SW2_U16];       // 26624 B; first 15360 B double as gather tile
    __shared__ __align__(16) unsigned short sH[EB * SH_STRIDE]; // 9216 B
    __shared__ __align__(16) unsigned short sF[EB * SF_STRIDE]; // 15360 B; sO overlays (stride 60 f32)
    __shared__ float sS1[EB][4];                                // 1024 B
    __shared__ int   sSrc[EB], sDst[EB];                        // 512 B

    const int tid  = threadIdx.x;
    const int lane = tid & 63;
    const int wv   = tid >> 6;
    const int m    = lane & 15;
    const int quad = lane >> 4;
    const int e0   = blockIdx.x * EB;
    const int em   = wv * 16 + m;          // block-local edge owned by this lane
    const int ew0  = e0 + wv * 16;

    if (tid < EB)            sSrc[tid]       = edge_index[e0 + tid];
    else if (tid < 2 * EB)   sDst[tid - EB]  = edge_index[NEDGE + e0 + tid - EB];
    __syncthreads();

    // ---- gather node rows into sG (overlays sW2; dead before staging) ----
    float* sG = (float*)sW2;
    {
        const float* nrow = node_attr + (size_t)sDst[em] * IRR;
        float* g = sG + em * SG_STRIDE;
        #pragma unroll
        for (int t = 0; t < 3; t++) {
            int c = quad + t * 4;
            *(float4*)(g + c * 4) = *(const float4*)(nrow + c * 4);
        }
        if (quad < 2) { int c = 12 + quad; *(float4*)(g + c * 4) = *(const float4*)(nrow + c * 4); }
    }

    // ---- GEMM1 transposed: lane holds H[e=em][hid] ----
    {
        const float* arow = edge_attr + (size_t)(ew0 + m) * EF;
        float av0[8], av1[8];
        {
            float4 p0 = *(const float4*)(arow + quad * 8);
            float4 p1 = *(const float4*)(arow + quad * 8 + 4);
            av0[0]=p0.x; av0[1]=p0.y; av0[2]=p0.z; av0[3]=p0.w;
            av0[4]=p1.x; av0[5]=p1.y; av0[6]=p1.z; av0[7]=p1.w;
        }
        if (quad < 2) {
            float4 p0 = *(const float4*)(arow + 32 + quad * 8);
            float4 p1 = *(const float4*)(arow + 32 + quad * 8 + 4);
            av1[0]=p0.x; av1[1]=p0.y; av1[2]=p0.z; av1[3]=p0.w;
            av1[4]=p1.x; av1[5]=p1.y; av1[6]=p1.z; av1[7]=p1.w;
        } else {
            #pragma unroll
            for (int j = 0; j < 8; j++) av1[j] = 0.f;
            if (quad == 2) av1[0] = 1.f;           // bias row k=48
        }
        u16x8 ub0, ub1;
        #pragma unroll
        for (int j = 0; j < 8; j++) { ub0[j] = f2bf(av0[j]); ub1[j] = f2bf(av1[j]); }
        bf16x8 hb0 = __builtin_bit_cast(bf16x8, ub0);
        bf16x8 hb1 = __builtin_bit_cast(bf16x8, ub1);

        #pragma unroll
        for (int nth = 0; nth < 3; nth++) {
            bf16x8 a0 = __builtin_bit_cast(bf16x8, *(const u16x8*)&W1T[(nth*16 + m)*64 + quad*8]);
            bf16x8 a1 = __builtin_bit_cast(bf16x8, *(const u16x8*)&W1T[(nth*16 + m)*64 + 32 + quad*8]);
            f32x4 c = {0.f, 0.f, 0.f, 0.f};
            c = __builtin_amdgcn_mfma_f32_16x16x32_bf16(a0, hb0, c, 0, 0, 0);
            c = __builtin_amdgcn_mfma_f32_16x16x32_bf16(a1, hb1, c, 0, 0, 0);
            u16x4 hp;
            #pragma unroll
            for (int r = 0; r < 4; r++) hp[r] = f2bf(fmaxf(c[r], 0.f));
            *(u16x4*)&sH[em * SH_STRIDE + nth*16 + quad*4] = hp;
        }
        if (quad == 3) {
            u16x4 b = {0x3F80, 0, 0, 0}, z = {0, 0, 0, 0};
            *(u16x4*)&sH[em * SH_STRIDE + 48] = b;
            *(u16x4*)&sH[em * SH_STRIDE + 52] = z;
            *(u16x4*)&sH[em * SH_STRIDE + 56] = z;
            *(u16x4*)&sH[em * SH_STRIDE + 60] = z;
        }
    }
    __syncthreads();

    // ---- F features (quad0 lanes), fp16 stores ----
    if (quad == 0) {
        const float* x = sG + em * SG_STRIDE;
        float4 sh4 = *(const float4*)&edge_sh[(size_t)(ew0 + m) * 4];
        const float s0 = sh4.x, sx = sh4.y, sy = sh4.z, sz = sh4.w;
        unsigned short* F = sF + em * SF_STRIDE;
        const float c0S = s0 * A_SCAL;
        const float c0V = s0 * A_VEC;
        const float cD3 = INV_SQRT3 * A_SCAL;
        const float cC2 = INV_SQRT2 * A_VEC;
        #pragma unroll
        for (int u = 0; u < 16; u++) {
            float x0e = x[u], x0o = x[40 + u];
            F[u]       = f2h(x0e * c0S);
            F[20 + u]  = f2h(x0e * A_VEC);
            F[84 + u]  = f2h(x0o * A_VEC);
            F[104 + u] = f2h(x0o * c0S);
        }
        #pragma unroll
        for (int u = 0; u < 4; u++) {
            float a0 = x[16 + u*3], a1 = x[16 + u*3 + 1], a2 = x[16 + u*3 + 2]; // x1o
            float b0 = x[28 + u*3], b1 = x[28 + u*3 + 1], b2 = x[28 + u*3 + 2]; // x1e
            F[16 + u]  = f2h((a0*sx + a1*sy + a2*sz) * cD3);
            F[100 + u] = f2h((b0*sx + b1*sy + b2*sz) * cD3);
            F[48 + u*3 + 0] = f2h((b1*sz - b2*sy) * cC2);
            F[48 + u*3 + 1] = f2h((b2*sx - b0*sz) * cC2);
            F[48 + u*3 + 2] = f2h((b0*sy - b1*sx) * cC2);
            F[60 + u*3 + 0] = f2h((a1*sz - a2*sy) * cC2);
            F[60 + u*3 + 1] = f2h((a2*sx - a0*sz) * cC2);
            F[60 + u*3 + 2] = f2h((a0*sy - a1*sx) * cC2);
            F[36 + u*3 + 0] = f2h(a0 * c0V);  F[36 + u*3 + 1] = f2h(a1 * c0V);  F[36 + u*3 + 2] = f2h(a2 * c0V);
            F[72 + u*3 + 0] = f2h(b0 * c0V);  F[72 + u*3 + 1] = f2h(b1 * c0V);  F[72 + u*3 + 2] = f2h(b2 * c0V);
        }
        sS1[em][0] = sx; sS1[em][1] = sy; sS1[em][2] = sz;
    }
    __syncthreads();

    bf16x8 HB0 = __builtin_bit_cast(bf16x8, *(const u16x8*)&sH[em * SH_STRIDE + quad*8]);
    bf16x8 HB1 = __builtin_bit_cast(bf16x8, *(const u16x8*)&sH[em * SH_STRIDE + 32 + quad*8]);
    __syncthreads();     // sG + sH dead; sW2 region free for staging

    // ---- fused GEMM2 + consume: 4 passes of 13 n-tiles, W2 staged in LDS ----
    float oe[4]  = {0.f,0.f,0.f,0.f};
    float oo[4]  = {0.f,0.f,0.f,0.f};
    float sA[4]  = {0.f,0.f,0.f,0.f};
    float sD[4]  = {0.f,0.f,0.f,0.f};
    float t1o[12] = {0.f,0.f,0.f,0.f,0.f,0.f,0.f,0.f,0.f,0.f,0.f,0.f};
    float t1e[12] = {0.f,0.f,0.f,0.f,0.f,0.f,0.f,0.f,0.f,0.f,0.f,0.f};

    const unsigned short* Fm = sF + em * SF_STRIDE;

    auto consume = [&](int nt, f32x4 c) {
        if (nt < 20) {                          // o0e
            float f = h2f(Fm[nt]);
            #pragma unroll
            for (int r = 0; r < 4; r++) oe[r] += f * c[r];
        } else if (nt < 24) {                   // wA1 dot
            float f = h2f(Fm[20 + (nt - 20)*4 + quad]);
            #pragma unroll
            for (int r = 0; r < 4; r++) sA[r] += f * c[r];
        } else if (nt < 26) {                   // wB1+wC1
            int u = (nt - 24)*4 + quad;
            #pragma unroll
            for (int i = 0; i < 3; i++) {
                float f = h2f(Fm[36 + u*3 + i]);
                #pragma unroll
                for (int r = 0; r < 4; r++) t1o[i*4 + r] += f * c[r];
            }
        } else if (nt < 28) {                   // wB1e+wC1e
            int j = (nt - 26)*4 + quad;
            #pragma unroll
            for (int i = 0; i < 3; i++) {
                float f = h2f(Fm[60 + j*3 + i]);
                #pragma unroll
                for (int r = 0; r < 4; r++) t1e[i*4 + r] += f * c[r];
            }
        } else if (nt < 32) {                   // wD1e dot
            float f = h2f(Fm[84 + (nt - 28)*4 + quad]);
            #pragma unroll
            for (int r = 0; r < 4; r++) sD[r] += f * c[r];
        } else {                                // o0o
            float f = h2f(Fm[68 + nt]);
            #pragma unroll
            for (int r = 0; r < 4; r++) oo[r] += f * c[r];
        }
    };

    const uint4* w2src = (const uint4*)W2L;
    uint4* w2dst = (uint4*)sW2;

    #pragma unroll 1
    for (int p = 0; p < NPASS; p++) {
        __syncthreads();                       // previous pass reads complete
        // stage 26624 B = 1664 uint4 with 256 threads (6.5 each)
        {
            const uint4* src = w2src + p * 1664;
            #pragma unroll
            for (int it = 0; it < 7; it++) {
                int idx = it * 256 + tid;
                if (idx < 1664) w2dst[idx] = src[idx];
            }
        }
        __syncthreads();

        #pragma unroll
        for (int i = 0; i < TPP; i++) {
            u16x8 A = *(const u16x8*)&sW2[i * 1024 + lane * 8];
            u16x8 B = *(const u16x8*)&sW2[i * 1024 + 512 + lane * 8];
            f32x4 c = {0.f, 0.f, 0.f, 0.f};
            c = __builtin_amdgcn_mfma_f32_16x16x32_bf16(__builtin_bit_cast(bf16x8, A), HB0, c, 0, 0, 0);
            c = __builtin_amdgcn_mfma_f32_16x16x32_bf16(__builtin_bit_cast(bf16x8, B), HB1, c, 0, 0, 0);
            consume(p * TPP + i, c);
        }
    }

    // ---- cross-quad butterfly (o1o/o1e paths) ----
    #pragma unroll
    for (int r = 0; r < 4; r++) {
        sA[r] += __shfl_xor(sA[r], 16, 64);  sA[r] += __shfl_xor(sA[r], 32, 64);
        sD[r] += __shfl_xor(sD[r], 16, 64);  sD[r] += __shfl_xor(sD[r], 32, 64);
    }
    #pragma unroll
    for (int i = 0; i < 12; i++) {
        t1o[i] += __shfl_xor(t1o[i], 16, 64);  t1o[i] += __shfl_xor(t1o[i], 32, 64);
        t1e[i] += __shfl_xor(t1e[i], 16, 64);  t1e[i] += __shfl_xor(t1e[i], 32, 64);
    }

    __syncthreads();                           // all sF reads done before sO overlay writes

    float* sO = (float*)sF;                    // stride 60 floats = 240B rows; f4 stores 16B-aligned
    {
        float4 v0; v0.x = oe[0]; v0.y = oe[1]; v0.z = oe[2]; v0.w = oe[3];
        float4 v1; v1.x = oo[0]; v1.y = oo[1]; v1.z = oo[2]; v1.w = oo[3];
        *(float4*)&sO[em * 60 + quad*4]      = v0;   // channels 0..15
        *(float4*)&sO[em * 60 + 40 + quad*4] = v1;   // channels 40..55
    }
    if (quad == 0) {
        float s1x = sS1[em][0], s1y = sS1[em][1], s1z = sS1[em][2];
        #pragma unroll
        for (int r = 0; r < 4; r++) {
            sO[em * 60 + 16 + r*3 + 0] = sA[r] * s1x + t1o[0*4 + r];
            sO[em * 60 + 16 + r*3 + 1] = sA[r] * s1y + t1o[1*4 + r];
            sO[em * 60 + 16 + r*3 + 2] = sA[r] * s1z + t1o[2*4 + r];
        }
    } else if (quad == 1) {
        float s1x = sS1[em][0], s1y = sS1[em][1], s1z = sS1[em][2];
        #pragma unroll
        for (int r = 0; r < 4; r++) {
            sO[em * 60 + 28 + r*3 + 0] = sD[r] * s1x + t1e[0*4 + r];
            sO[em * 60 + 28 + r*3 + 1] = sD[r] * s1y + t1e[1*4 + r];
            sO[em * 60 + 28 + r*3 + 2] = sD[r] * s1z + t1e[2*4 + r];
        }
    }
    __syncthreads();

    // ---- channel-major coalesced atomic scatter (line-merged, R4-verified) ----
    #pragma unroll
    for (int it = 0; it < 14; it++) {
        int idx = it * NT + tid;               // < 3584 = 64*56
        int e = idx / IRR, ch = idx - e * IRR;
        unsafeAtomicAdd(&accum[(size_t)sSrc[e] * IRR + ch], sO[e * 60 + ch]);
    }
    if (tid < EB) unsafeAtomicAdd(&counts[sSrc[tid]], 1.0f);
}

__global__ void tp_divide(const float* __restrict__ accum,
                          const float* __restrict__ counts,
                          float* __restrict__ out)
{
    int idx = blockIdx.x * blockDim.x + threadIdx.x;
    if (idx < NNODE * IRR) {
        out[idx] = accum[idx] / fmaxf(counts[idx / IRR], 1.0f);
    }
}

extern "C" void kernel_launch(void* const* d_in, const int* in_sizes, int n_in,
                              void* d_out, int out_size, void* d_ws, size_t ws_size,
                              hipStream_t stream) {
    const float* node_attr  = (const float*)d_in[0];
    const float* edge_attr  = (const float*)d_in[1];
    const float* edge_sh    = (const float*)d_in[2];
    const float* fc_w1      = (const float*)d_in[3];
    const float* fc_b1      = (const float*)d_in[4];
    const float* fc_w2      = (const float*)d_in[5];
    const float* fc_b2      = (const float*)d_in[6];
    const int*   edge_index = (const int*)d_in[7];

    float* accum  = (float*)d_ws;                              // 448000 f
    float* counts = accum + (size_t)NNODE * IRR;               // 8000 f
    unsigned short* W1T = (unsigned short*)(counts + NNODE);   // 48*64
    unsigned short* W2L = W1T + EF * 64;                       // 52*2*64*8 = 53248

    k_setup<<<(NNODE * IRR + NNODE + 255) / 256, 256, 0, stream>>>(
        fc_w1, fc_b1, fc_w2, fc_b2, W1T, W2L, accum);

    tp_fused<<<NBLK, NT, 0, stream>>>(node_attr, edge_attr, edge_sh, edge_index,
                                      W1T, W2L, accum, counts);

    tp_divide<<<(NNODE * IRR + 255) / 256, 256, 0, stream>>>(accum, counts, (float*)d_out);
}